// Round 17
// baseline (205.522 us; speedup 1.0000x reference)
//
#include <hip/hip_runtime.h>

#define T_DIM 2048
#define D_DIM 1024
#define H_DIM 1024
#define B_DIM 4

typedef __attribute__((ext_vector_type(8))) __bf16 bf16x8;
typedef __attribute__((ext_vector_type(4))) float f32x4;
typedef __attribute__((ext_vector_type(8))) unsigned short us8;

__device__ __forceinline__ unsigned short f2b(float f) {
  union { float f; unsigned int u; } x; x.f = f;
  unsigned int r = x.u + 0x7fffu + ((x.u >> 16) & 1u);
  return (unsigned short)(r >> 16);
}
__device__ __forceinline__ float b2f(unsigned short b) {
  union { unsigned int u; float f; } x; x.u = ((unsigned int)b) << 16;
  return x.f;
}

__device__ __forceinline__ void async16(unsigned short* l, const unsigned short* g) {
  __builtin_amdgcn_global_load_lds((const __attribute__((address_space(1))) void*)g,
                                   (__attribute__((address_space(3))) void*)l,
                                   16, 0, 0);
}

// ---------------- fused input prep: weights cvt + bias concat + xT transpose ----------------
__global__ __launch_bounds__(256) void prep_kernel(const float* __restrict__ ew,
                                                   const float* __restrict__ kw,
                                                   const float* __restrict__ qw,
                                                   const float* __restrict__ vw,
                                                   const float* __restrict__ kb,
                                                   const float* __restrict__ qb,
                                                   const float* __restrict__ vb,
                                                   const float* __restrict__ X,
                                                   unsigned short* __restrict__ oe,
                                                   unsigned short* __restrict__ okqv,
                                                   float* __restrict__ ob,
                                                   unsigned short* __restrict__ xT) {
  __shared__ float tile[32][33];
  int bid = blockIdx.x;
  if (bid < 4096) {                 // weight cvt: float4 index over 4 x 256K
    int i = bid * 256 + threadIdx.x;
    int seg = i >> 18;
    int off = i & 262143;
    const float* in = seg == 0 ? ew : (seg == 1 ? kw : (seg == 2 ? qw : vw));
    unsigned short* out = seg == 0 ? oe : okqv + (size_t)(seg - 1) * 1048576;
    float4 v = ((const float4*)in)[off];
    ushort4 o;
    o.x = f2b(v.x); o.y = f2b(v.y); o.z = f2b(v.z); o.w = f2b(v.w);
    ((ushort4*)out)[off] = o;
    return;
  }
  if (bid == 4096) {                // bias concat: 3072 floats
    #pragma unroll
    for (int k = 0; k < 3; k++) {
      int f4 = threadIdx.x + k * 256;
      int fi = f4 * 4;
      const float* src = fi < 1024 ? kb + fi : (fi < 2048 ? qb + (fi - 1024) : vb + (fi - 2048));
      *(float4*)(&ob[fi]) = *(const float4*)src;
    }
    return;
  }
  // xT transpose
  int v = bid - 4097;
  int c0 = (v & 63) * 32;           // t
  int r0 = ((v >> 6) & 31) * 32;    // h
  int z  = v >> 11;                 // batch
  int tx = threadIdx.x & 31, ty = threadIdx.x >> 5;
  const float* I = X + (size_t)z * H_DIM * T_DIM;
  #pragma unroll
  for (int i = 0; i < 32; i += 8)
    tile[ty + i][tx] = I[(size_t)(r0 + ty + i) * T_DIM + (c0 + tx)];
  __syncthreads();
  unsigned short* O = xT + (size_t)z * T_DIM * H_DIM;
  #pragma unroll
  for (int i = 0; i < 32; i += 8)
    O[(size_t)(c0 + ty + i) * H_DIM + (r0 + tx)] = f2b(tile[tx][ty + i]);
}

#define BAR_ asm volatile("s_barrier" ::: "memory")
#define VM8_ asm volatile("s_waitcnt vmcnt(8)" ::: "memory")
#define VM6_ asm volatile("s_waitcnt vmcnt(6)" ::: "memory")
#define VM4_ asm volatile("s_waitcnt vmcnt(4)" ::: "memory")
#define VM0_ asm volatile("s_waitcnt vmcnt(0)" ::: "memory")

#define FRG(base, row, ks) \
  (*(const bf16x8*)((base) + (row) * 64 + ((((ks) << 2) | hi) ^ (lo & 7)) * 8))

// ---- 128x256 triple-buffer core macros ----
#define STGA3(t, bb, u) async16(smem + (bb) * 24576 + (u) * 4096 + tid * 8, \
                                A + (size_t)((u) * 64 + rl0) * lda + (t) * 64 + ce)
#define STGB3(t, bb, u) async16(smem + (bb) * 24576 + 8192 + (u) * 4096 + tid * 8, \
                                Bm + (size_t)((u) * 64 + rl0) * ldb + (t) * 64 + ce)
#define STGTILE(t, bb) do { STGA3(t, bb, 0); STGA3(t, bb, 1); \
    STGB3(t, bb, 0); STGB3(t, bb, 1); STGB3(t, bb, 2); STGB3(t, bb, 3); } while (0)

#define LOADFRAGS(bA, bB)                                            \
  _Pragma("unroll") for (int m_ = 0; m_ < 4; m_++) {                 \
    af[m_][0] = FRG(bA, wr * 64 + m_ * 16 + lo, 0);                  \
    af[m_][1] = FRG(bA, wr * 64 + m_ * 16 + lo, 1);                  \
  }                                                                  \
  _Pragma("unroll") for (int n_ = 0; n_ < 4; n_++) {                 \
    bg[n_][0] = FRG(bB, wc * 64 + n_ * 16 + lo, 0);                  \
    bg[n_][1] = FRG(bB, wc * 64 + n_ * 16 + lo, 1);                  \
  }

#define MFMA32_                                                          \
  __builtin_amdgcn_s_setprio(1);                                         \
  _Pragma("unroll") for (int ks_ = 0; ks_ < 2; ks_++)                    \
    _Pragma("unroll") for (int m_ = 0; m_ < 4; m_++)                     \
      _Pragma("unroll") for (int n_ = 0; n_ < 4; n_++)                   \
        acc[m_][n_] = __builtin_amdgcn_mfma_f32_16x16x32_bf16(           \
            af[m_][ks_], bg[n_][ks_], acc[m_][n_], 0, 0, 0);             \
  __builtin_amdgcn_s_setprio(0);

// 128x256 triple-buffer GEMM body (OMODE 1: col bias; 3: row bias).
#define GEMM8_BODY(OMODE, Apar, Bpar, biasPar, CbPar, Npar, Kpar, ldaPar, ldbPar, flatPar, gxPar, gyPar) \
  do {                                                                                 \
    int nwg = (gxPar) * (gyPar);                                                       \
    int cpx = nwg >> 3;                                                                \
    int f2 = ((flatPar) & 7) * cpx + ((flatPar) >> 3);                                 \
    int bn = f2 % (gxPar), bm = f2 / (gxPar);                                          \
    const unsigned short* A  = (Apar) + (size_t)bm * 128 * (ldaPar);                   \
    const unsigned short* Bm = (Bpar) + (size_t)bn * 256 * (ldbPar);                   \
    int lda = (ldaPar), ldb = (ldbPar);                                                \
    int nt = (Kpar) / 64;                                                              \
    bf16x8 af[4][2], bg[4][2];                                                         \
    f32x4 acc[4][4] = {};                                                              \
    STGTILE(0, 0);                                                                     \
    STGTILE(1, 1);                                                                     \
    VM6_; BAR_;                                                                        \
    int cur = 0;                                                                       \
    for (int t = 0; t < nt - 2; t++) {                                                 \
      const unsigned short* bA = smem + cur * 24576;                                   \
      const unsigned short* bB = bA + 8192;                                            \
      LOADFRAGS(bA, bB)                                                                \
      int b2 = cur + 2; if (b2 >= 3) b2 -= 3;                                          \
      STGTILE(t + 2, b2);                                                              \
      MFMA32_                                                                          \
      VM6_; BAR_;                                                                      \
      cur = (cur + 1 == 3) ? 0 : cur + 1;                                              \
    }                                                                                  \
    {                                                                                  \
      const unsigned short* bA = smem + cur * 24576;                                   \
      const unsigned short* bB = bA + 8192;                                            \
      LOADFRAGS(bA, bB)                                                                \
      MFMA32_                                                                          \
      VM0_; BAR_;                                                                      \
      cur = (cur + 1 == 3) ? 0 : cur + 1;                                              \
    }                                                                                  \
    {                                                                                  \
      const unsigned short* bA = smem + cur * 24576;                                   \
      const unsigned short* bB = bA + 8192;                                            \
      LOADFRAGS(bA, bB)                                                                \
      MFMA32_                                                                          \
    }                                                                                  \
    __syncthreads();                                                                   \
    int row0 = bm * 128, col0 = bn * 256;                                              \
    unsigned short* ep = smem;                                                         \
    _Pragma("unroll") for (int n = 0; n < 4; n++) {                                    \
      int cl = wc * 64 + n * 16 + lo;                                                  \
      float bvc = ((OMODE) == 1) ? (biasPar)[col0 + cl] : 0.f;                         \
      _Pragma("unroll") for (int m = 0; m < 4; m++) {                                  \
        int rl = wr * 64 + m * 16 + hi * 4;                                            \
        _Pragma("unroll") for (int j = 0; j < 4; j++) {                                \
          float bv = ((OMODE) == 3) ? (biasPar)[row0 + rl + j] : bvc;                  \
          ep[(rl + j) * 264 + cl] = f2b(acc[m][n][j] + bv);                            \
        }                                                                              \
      }                                                                                \
    }                                                                                  \
    __syncthreads();                                                                   \
    _Pragma("unroll") for (int it = 0; it < 8; it++) {                                 \
      int idx = it * 512 + tid, r = idx >> 5, c = idx & 31;                            \
      *(uint4*)((CbPar) + (size_t)(row0 + r) * (Npar) + col0 + c * 8) =                \
          *(const uint4*)(ep + r * 264 + c * 8);                                       \
    }                                                                                  \
  } while (0)

template <int OMODE>
__global__ __launch_bounds__(512, 2)
void gemm8_kernel(const unsigned short* __restrict__ Ag,
                  const unsigned short* __restrict__ Bg,
                  const float* __restrict__ bias,
                  unsigned short* __restrict__ Cb,
                  int N, int K, int lda_, int ldb_) {
  __shared__ __align__(16) unsigned short smem[73728];   // 144 KiB
  int tid = threadIdx.x;
  int lane = tid & 63, wid = tid >> 6;
  int wr = wid >> 2, wc = wid & 3;
  int lo = lane & 15, hi = lane >> 4;
  int rl0 = tid >> 3;
  int ce = 8 * ((tid & 7) ^ (rl0 & 7));
  int flat = blockIdx.x + gridDim.x * blockIdx.y;
  GEMM8_BODY(OMODE, Ag, Bg, bias, Cb, N, K, lda_, ldb_, flat, (int)gridDim.x, (int)gridDim.y);
}

// ---- 256x256 8-phase core macros (R7-validated ledger) ----
#define STGAH(t, h) do { \
    unsigned short* d_ = ldsA + ((t) & 1) * 16384 + (h) * 8192 + tid * 8;            \
    const unsigned short* s_ = A + (size_t)((h) * 128 + rl0) * lda + (t) * 64 + ce;  \
    async16(d_, s_); async16(d_ + 4096, s_ + (size_t)64 * lda); } while (0)
#define STGBH(t, h) do { \
    unsigned short* d_ = ldsB + ((t) & 1) * 16384 + (h) * 8192 + tid * 8;            \
    const unsigned short* s_ = Bm + (size_t)((h) * 128 + rl0) * ldb + (t) * 64 + ce; \
    async16(d_, s_); async16(d_ + 4096, s_ + (size_t)64 * ldb); } while (0)

#define LDA_(bA, mb)                                                   \
  _Pragma("unroll") for (int m_ = 0; m_ < 4; m_++) {                   \
    int row_ = wr * 128 + ((mb) + m_) * 16 + lo;                       \
    af[m_][0] = FRG(bA, row_, 0);                                      \
    af[m_][1] = FRG(bA, row_, 1);                                      \
  }

#define LDB_(bB, nb, bgv)                                              \
  _Pragma("unroll") for (int n_ = 0; n_ < 2; n_++) {                   \
    int row_ = wc * 64 + ((nb) + n_) * 16 + lo;                        \
    bgv[n_][0] = FRG(bB, row_, 0);                                     \
    bgv[n_][1] = FRG(bB, row_, 1);                                     \
  }

#define MM_(mb, nb, bgv)                                                             \
  __builtin_amdgcn_s_setprio(1);                                                     \
  _Pragma("unroll") for (int m_ = 0; m_ < 4; m_++)                                   \
    _Pragma("unroll") for (int n_ = 0; n_ < 2; n_++) {                               \
      acc[(mb) + m_][(nb) + n_] = __builtin_amdgcn_mfma_f32_16x16x32_bf16(           \
          af[m_][0], bgv[n_][0], acc[(mb) + m_][(nb) + n_], 0, 0, 0);                \
      acc[(mb) + m_][(nb) + n_] = __builtin_amdgcn_mfma_f32_16x16x32_bf16(           \
          af[m_][1], bgv[n_][1], acc[(mb) + m_][(nb) + n_], 0, 0, 0);                \
    }                                                                                \
  __builtin_amdgcn_s_setprio(0);

#define GEMML_BODY(BIAS, Apar, Bpar, biasPar, CbPar, Npar, Kpar, ldaPar, ldbPar, bnv, bmv, coffPar) \
  do {                                                                                 \
    const unsigned short* A  = (Apar) + (size_t)(bmv) * 256 * (ldaPar);                \
    const unsigned short* Bm = (Bpar) + (size_t)(bnv) * 256 * (ldbPar);                \
    int lda = (ldaPar), ldb = (ldbPar);                                                \
    unsigned short* ldsA = smem;                                                       \
    unsigned short* ldsB = smem + 32768;                                               \
    int nt = (Kpar) / 64;                                                              \
    bf16x8 af[4][2], bg0[2][2], bg1[2][2];                                             \
    f32x4 acc[8][4] = {};                                                              \
    STGAH(0, 0); STGAH(0, 1); STGBH(0, 0); STGBH(0, 1);                                \
    STGAH(1, 0); STGAH(1, 1); STGBH(1, 0); STGBH(1, 1);                                \
    VM8_; BAR_;                                                                        \
    const unsigned short* bA0 = ldsA;                                                  \
    const unsigned short* bB0 = ldsB;                                                  \
    const unsigned short* bA1 = ldsA + 16384;                                          \
    const unsigned short* bB1 = ldsB + 16384;                                          \
    int nIter = nt >> 1;                                                               \
    for (int i = 0; i < nIter; i++) {                                                  \
      bool last = (i == nIter - 1);                                                    \
      int ta = 2 * i, tb = ta + 1;                                                     \
      LDA_(bA0, 0) LDB_(bB0, 0, bg0)                                                   \
      BAR_; MM_(0, 0, bg0) BAR_;                                                       \
      LDB_(bB0, 2, bg1)                                                                \
      BAR_; MM_(0, 2, bg1) BAR_;                                                       \
      LDA_(bA0, 4)                                                                     \
      if (!last) STGBH(ta + 2, 0);                                                     \
      BAR_; MM_(4, 0, bg0) BAR_;                                                       \
      if (!last) { STGAH(ta + 2, 0); STGBH(ta + 2, 1); }                               \
      BAR_; MM_(4, 2, bg1)                                                             \
      if (last) { VM0_; } else { VM6_; }                                               \
      BAR_;                                                                            \
      LDA_(bA1, 0) LDB_(bB1, 0, bg0)                                                   \
      if (!last) STGAH(ta + 2, 1);                                                     \
      BAR_; MM_(0, 0, bg0) BAR_;                                                       \
      LDB_(bB1, 2, bg1)                                                                \
      BAR_; MM_(0, 2, bg1) BAR_;                                                       \
      LDA_(bA1, 4)                                                                     \
      if (!last) STGBH(tb + 2, 0);                                                     \
      BAR_; MM_(4, 0, bg0) BAR_;                                                       \
      if (!last) { STGAH(tb + 2, 0); STGBH(tb + 2, 1); STGAH(tb + 2, 1); }             \
      BAR_; MM_(4, 2, bg1)                                                             \
      if (!last) VM8_;                                                                 \
      BAR_;                                                                            \
    }                                                                                  \
    __syncthreads();                                                                   \
    int row0 = (bmv) * 256, col0 = (bnv) * 256;                                        \
    unsigned short* ep = smem;                                                         \
    _Pragma("unroll") for (int half = 0; half < 2; half++) {                           \
      __syncthreads();                                                                 \
      if (wr == half) {                                                                \
        _Pragma("unroll") for (int n = 0; n < 4; n++) {                                \
          int cl = wc * 64 + n * 16 + lo;                                              \
          float bv = (BIAS) ? (biasPar)[col0 + cl] : 0.f;                              \
          _Pragma("unroll") for (int m = 0; m < 8; m++) {                              \
            int rl = m * 16 + hi * 4;                                                  \
            _Pragma("unroll") for (int j = 0; j < 4; j++)                              \
              ep[(rl + j) * 264 + cl] = f2b(acc[m][n][j] + bv);                        \
          }                                                                            \
        }                                                                              \
      }                                                                                \
      __syncthreads();                                                                 \
      _Pragma("unroll") for (int it = 0; it < 8; it++) {                               \
        int idx = it * 512 + tid, r = idx >> 5, c = idx & 31;                          \
        *(uint4*)((CbPar) + (coffPar) + (size_t)(row0 + half * 128 + r) * (Npar) +     \
                  col0 + c * 8) = *(const uint4*)(ep + r * 264 + c * 8);               \
      }                                                                                \
    }                                                                                  \
  } while (0)

// KQ = m @ [Wk;Wq]^T + b : standalone, 256 blocks (1 exact round)
__global__ __launch_bounds__(512, 2)
void gemmKQ_kernel(const unsigned short* __restrict__ m_bf,
                   const unsigned short* __restrict__ wbf_kqv,
                   const float* __restrict__ kqv_b,
                   unsigned short* __restrict__ KQ) {
  __shared__ __align__(16) unsigned short smem[73728];
  int tid = threadIdx.x;
  int lane = tid & 63, wid = tid >> 6;
  int wr = wid >> 2, wc = wid & 3;
  int lo = lane & 15, hi = lane >> 4;
  int rl0 = tid >> 3;
  int ce = 8 * ((tid & 7) ^ (rl0 & 7));
  int flat = blockIdx.x;
  int f2x = (flat & 7) * 32 + (flat >> 3);
  int bn = f2x % 8, bm = f2x / 8;
  GEMML_BODY(true, m_bf, wbf_kqv, kqv_b, KQ, 2048, D_DIM, D_DIM, D_DIM, bn, bm,
             (size_t)0);
}

// Merged VTd (blocks 0..255, 128x256 core) + logits (blocks 256..511, 256^2 core).
__global__ __launch_bounds__(512, 2)
void lvt_kernel(const unsigned short* __restrict__ KQ,
                const unsigned short* __restrict__ m_bf,
                const unsigned short* __restrict__ wbf_kqv,
                const float* __restrict__ value_b,
                unsigned short* __restrict__ logits_bf,
                unsigned short* __restrict__ VTd) {
  __shared__ __align__(16) unsigned short smem[73728];
  int tid = threadIdx.x;
  int lane = tid & 63, wid = tid >> 6;
  int wr = wid >> 2, wc = wid & 3;
  int lo = lane & 15, hi = lane >> 4;
  int rl0 = tid >> 3;
  int ce = 8 * ((tid & 7) ^ (rl0 & 7));

  if (blockIdx.x < 256) {
    // VTd[d][bt] = Wv[d]·m[bt] + vb[d] : M=1024 (8 tiles of 128), N=8192 (32 tiles)
    int flat = blockIdx.x;
    GEMM8_BODY(3, wbf_kqv + 2 * 1024 * 1024, m_bf, value_b, VTd, 8192, D_DIM,
               D_DIM, D_DIM, flat, 32, 8);
  } else {
    // logitsT[b][s][t] = K[b,s]·Q[b,t], causal skip (bn<bm)
    int lbid = blockIdx.x - 256;
    int bz = lbid >> 6;
    int flat = lbid & 63;
    int f2x = (flat & 7) * 8 + (flat >> 3);
    int bn = f2x % 8, bm = f2x / 8;
    if (bn < bm) return;
    const unsigned short* Ab = KQ + (size_t)bz * T_DIM * 2048;
    const unsigned short* Bb = KQ + 1024 + (size_t)bz * T_DIM * 2048;
    GEMML_BODY(false, Ab, Bb, (const float*)nullptr, logits_bf, T_DIM, D_DIM,
               2048, 2048, bn, bm, (size_t)bz * T_DIM * T_DIM);
  }
}

// ============ Paired causal PV (R11/R13 version, measured 39us) ============
#define PSTGA(t, bb, u) async16(smem + (bb) * 16384 + (u) * 4096 + tid * 8, \
                                Ap + (size_t)((u) * 64 + rl0) * T_DIM + (t) * 64 + ce)
#define PSTGB(t, bb, u) async16(smem + (bb) * 16384 + 8192 + (u) * 4096 + tid * 8, \
                                Bp + (size_t)((u) * 64 + rl0) * 8192 + (t) * 64 + ce)
#define PSTG(t, bb) do { PSTGA(t, bb, 0); PSTGA(t, bb, 1); \
                         PSTGB(t, bb, 0); PSTGB(t, bb, 1); } while (0)

#define PVFRAGS(bA, bB)                                              \
  _Pragma("unroll") for (int m_ = 0; m_ < 4; m_++) {                 \
    af[m_][0] = FRG(bA, wr * 64 + m_ * 16 + lo, 0);                  \
    af[m_][1] = FRG(bA, wr * 64 + m_ * 16 + lo, 1);                  \
  }                                                                  \
  _Pragma("unroll") for (int n_ = 0; n_ < 2; n_++) {                 \
    bg[n_][0] = FRG(bB, wc * 32 + n_ * 16 + lo, 0);                  \
    bg[n_][1] = FRG(bB, wc * 32 + n_ * 16 + lo, 1);                  \
  }

#define PVMFMA_                                                          \
  __builtin_amdgcn_s_setprio(1);                                         \
  _Pragma("unroll") for (int ks_ = 0; ks_ < 2; ks_++)                    \
    _Pragma("unroll") for (int m_ = 0; m_ < 4; m_++)                     \
      _Pragma("unroll") for (int n_ = 0; n_ < 2; n_++)                   \
        acc[m_][n_] = __builtin_amdgcn_mfma_f32_16x16x32_bf16(           \
            af[m_][ks_], bg[n_][ks_], acc[m_][n_], 0, 0, 0);             \
  __builtin_amdgcn_s_setprio(0);

__global__ __launch_bounds__(512, 2)
void pv_kernel(const unsigned short* __restrict__ probs,
               const unsigned short* __restrict__ VTd,
               const unsigned short* __restrict__ mres,
               float* __restrict__ out) {
  __shared__ __align__(16) unsigned short smem[49152];   // 96 KiB
  int bn = blockIdx.x;        // d-tile (128 wide), 0..7
  int jj = blockIdx.y;        // pair id 0..7
  int bz = blockIdx.z;
  int tid = threadIdx.x;
  int lane = tid & 63, wid = tid >> 6;
  int wr = wid >> 2, wc = wid & 3;      // wr: t-half, wc: d-quarter
  int lo = lane & 15, hi = lane >> 4;
  int rl0 = tid >> 3;
  int ce = 8 * ((tid & 7) ^ (rl0 & 7));

  const unsigned short* Bp = VTd + (size_t)(bn * 128) * 8192 + bz * T_DIM;

  #pragma unroll 1
  for (int seg = 0; seg < 2; seg++) {
    int jt = (seg == 0) ? jj : (15 - jj);
    int nt = ((seg == 0) ? (jj + 1) : (16 - jj)) * 2;
    const unsigned short* Ap = probs + (size_t)bz * T_DIM * T_DIM + (size_t)(jt * 128) * T_DIM;

    bf16x8 af[4][2], bg[2][2];
    f32x4 acc[4][2] = {};

    PSTG(0, 0);
    PSTG(1, 1);
    VM4_; BAR_;

    int cur = 0;
    for (int t = 0; t < nt - 2; t++) {
      const unsigned short* bA = smem + cur * 16384;
      const unsigned short* bB = bA + 8192;
      PVFRAGS(bA, bB)
      int b2 = cur + 2; if (b2 >= 3) b2 -= 3;
      PSTG(t + 2, b2);
      PVMFMA_
      VM4_; BAR_;
      cur = (cur + 1 == 3) ? 0 : cur + 1;
    }
    {
      const unsigned short* bA = smem + cur * 16384;
      const unsigned short* bB = bA + 8192;
      PVFRAGS(bA, bB)
      PVMFMA_
      VM0_; BAR_;
      cur = (cur + 1 == 3) ? 0 : cur + 1;
    }
    {
      const unsigned short* bA = smem + cur * 16384;
      const unsigned short* bB = bA + 8192;
      PVFRAGS(bA, bB)
      PVMFMA_
    }

    __syncthreads();
    float* ep = (float*)smem;   // [128 d][132 t]
    #pragma unroll
    for (int n = 0; n < 2; n++) {
      int dl = wc * 32 + n * 16 + lo;
      #pragma unroll
      for (int m = 0; m < 4; m++) {
        int tl = wr * 64 + m * 16 + hi * 4;
        #pragma unroll
        for (int j = 0; j < 4; j++) {
          float v = acc[m][n][j] +
              b2f(mres[((size_t)bz * T_DIM + jt * 128 + tl + j) * D_DIM + bn * 128 + dl]);
          ep[dl * 132 + tl + j] = v;
        }
      }
    }
    __syncthreads();
    #pragma unroll
    for (int it = 0; it < 8; it++) {
      int idx = it * 512 + tid, r = idx >> 5, c = idx & 31;
      *(float4*)(out + ((size_t)bz * D_DIM + bn * 128 + r) * T_DIM + jt * 128 + c * 4) =
          *(const float4*)(ep + r * 132 + c * 4);
    }
    __syncthreads();
  }
}

// ---------------- softmax stats (bf16 logitsT rows, causal start) ----------------
__device__ __forceinline__ float wred_max(float v) {
  #pragma unroll
  for (int o = 32; o > 0; o >>= 1) v = fmaxf(v, __shfl_down(v, o, 64));
  return v;
}
__device__ __forceinline__ float wred_sum(float v) {
  #pragma unroll
  for (int o = 32; o > 0; o >>= 1) v += __shfl_down(v, o, 64);
  return v;
}

__global__ __launch_bounds__(256) void softmax_stats_kernel(const unsigned short* __restrict__ lg,
                                                            float* __restrict__ smax,
                                                            float* __restrict__ sinv) {
  __shared__ float sb[4];
  int row = blockIdx.x;            // b*T + s
  int s = row & (T_DIM - 1);
  int t0 = s & ~255;               // 256-aligned causal floor
  int n8 = (T_DIM - t0) >> 3;
  float x[8];
  float mx = -3.4e38f;
  if (threadIdx.x < n8) {
    us8 v = ((const us8*)(lg + (size_t)row * T_DIM + t0))[threadIdx.x];
    int tb = t0 + threadIdx.x * 8;
    #pragma unroll
    for (int j = 0; j < 8; j++) {
      x[j] = (tb + j >= s) ? b2f(v[j]) : -3.4e38f;
      mx = fmaxf(mx, x[j]);
    }
  } else {
    #pragma unroll
    for (int j = 0; j < 8; j++) x[j] = -3.4e38f;
  }
  mx = wred_max(mx);
  if ((threadIdx.x & 63) == 0) sb[threadIdx.x >> 6] = mx;
  __syncthreads();
  mx = fmaxf(fmaxf(sb[0], sb[1]), fmaxf(sb[2], sb[3]));
  __syncthreads();
  float sum = 0.f;
  #pragma unroll
  for (int j = 0; j < 8; j++) sum += __expf(x[j] - mx);
  sum = wred_sum(sum);
  if ((threadIdx.x & 63) == 0) sb[threadIdx.x >> 6] = sum;
  __syncthreads();
  if (threadIdx.x == 0) {
    float tot = sb[0] + sb[1] + sb[2] + sb[3];
    smax[row] = mx;
    sinv[row] = 1.0f / (tot * 32.0f);
  }
}

// ---------------- normalize + transpose (vectorized): probs[t][s] bf16 ----------------
// 64x64 tiles; us8 loads from logitsT rows, us8 stores to probs rows.
__global__ __launch_bounds__(256) void probs_kernel(const unsigned short* __restrict__ lg,
                                                    const float* __restrict__ smax,
                                                    const float* __restrict__ sinv,
                                                    unsigned short* __restrict__ probs) {
  int bz = blockIdx.z;
  int t0 = blockIdx.x * 64, s0 = blockIdx.y * 64;
  // PV reads probs[t][s] for s < (jt+1)*128 where jt = t>>7; skip tiles wholly beyond.
  if (s0 >= ((((t0 + 63) >> 7) + 1) << 7)) return;
  __shared__ unsigned short tile[64][72];   // [s_local][t_local+pad]
  int tid = threadIdx.x;
  const unsigned short* L = lg + (size_t)bz * T_DIM * T_DIM;
  #pragma unroll
  for (int p = 0; p < 2; p++) {
    int idx = p * 256 + tid;
    int r = idx >> 3, c = idx & 7;       // row s0+r, t-chunk c
    us8 v = *(const us8*)(L + (size_t)(s0 + r) * T_DIM + t0 + c * 8);
    *(us8*)(&tile[r][c * 8]) = v;
  }
  __syncthreads();
  unsigned short* P = probs + (size_t)bz * T_DIM * T_DIM;
  const float* SM = smax + bz * T_DIM;
  const float* SI = sinv + bz * T_DIM;
  #pragma unroll
  for (int p = 0; p < 2; p++) {
    int idx = p * 256 + tid;
    int tl = idx >> 3, c = idx & 7;      // output row t0+tl, s-chunk c
    int t = t0 + tl;
    us8 o;
    #pragma unroll
    for (int j = 0; j < 8; j++) {
      int s = s0 + c * 8 + j;
      float x = b2f(tile[c * 8 + j][tl]);
      float pv = (t >= s) ? __expf(x - SM[s]) * SI[s] : 0.f;
      o[j] = f2b(pv);
    }
    *(us8*)(P + (size_t)t * T_DIM + s0 + c * 8) = o;
  }
}

extern "C" void kernel_launch(void* const* d_in, const int* in_sizes, int n_in,
                              void* d_out, int out_size, void* d_ws, size_t ws_size,
                              hipStream_t stream) {
  const float* minibatch = (const float*)d_in[0];
  const float* emb_w   = (const float*)d_in[1];
  const float* emb_b   = (const float*)d_in[2];
  const float* key_w   = (const float*)d_in[3];
  const float* key_b   = (const float*)d_in[4];
  const float* query_w = (const float*)d_in[5];
  const float* query_b = (const float*)d_in[6];
  const float* value_w = (const float*)d_in[7];
  const float* value_b = (const float*)d_in[8];
  float* out = (float*)d_out;

  char* ws = (char*)d_ws;
  const size_t MB = 1ull << 20;
  unsigned short* wbf_emb = (unsigned short*)(ws + 0 * MB);    // 2 MB
  unsigned short* wbf_kqv = (unsigned short*)(ws + 2 * MB);    // 6 MB [key|query|value]
  float*          kqv_b   = (float*)(ws + 8 * MB);
  unsigned short* m_bf    = (unsigned short*)(ws + 9 * MB);    // 16 MB, live to end
  unsigned short* KQ      = (unsigned short*)(ws + 25 * MB);   // 32 MB [8192][2048]
  unsigned short* VTd     = (unsigned short*)(ws + 57 * MB);   // 16 MB [1024][8192]
  unsigned short* logits_bf = (unsigned short*)(ws + 89 * MB); // 32 MB
  unsigned short* xT      = (unsigned short*)(ws + 153 * MB);  // 16 MB (dead after emb)
  unsigned short* probs   = (unsigned short*)(ws + 153 * MB);  // 32 MB, aliases xT
  float*          smax    = (float*)(ws + 186 * MB);
  float*          sinv    = (float*)(ws + 186 * MB + 32768);

  const int BT = B_DIM * T_DIM;   // 8192

  // 1) fused: weights -> bf16, bias concat, xT transpose
  prep_kernel<<<12289, 256, 0, stream>>>(emb_w, key_w, query_w, value_w,
                                         key_b, query_b, value_b, minibatch,
                                         wbf_emb, wbf_kqv, kqv_b, xT);

  // 2) m = xT @ emb_w^T + emb_b  -- 128x256 tile, 256 blocks, 1 round
  gemm8_kernel<1><<<dim3(D_DIM / 256, BT / 128, 1), 512, 0, stream>>>(
      xT, wbf_emb, emb_b, m_bf, D_DIM, H_DIM, H_DIM, H_DIM);

  // 3) KQ = m @ [Wk;Wq]^T + b  -- 256^2 core, 256 blocks, 1 exact round
  gemmKQ_kernel<<<256, 512, 0, stream>>>(m_bf, wbf_kqv, kqv_b, KQ);

  // 4) merged: VTd (blocks 0..255) + logits (blocks 256..511, causal skip)
  lvt_kernel<<<512, 512, 0, stream>>>(KQ, m_bf, wbf_kqv, value_b, logits_bf, VTd);

  // 5) column-softmax stats (causal-trimmed reads)
  softmax_stats_kernel<<<BT, 256, 0, stream>>>(logits_bf, smax, sinv);

  // 6) probs[b][t][s] bf16, transposed (vectorized 64x64 tiles)
  probs_kernel<<<dim3(T_DIM / 64, T_DIM / 64, B_DIM), 256, 0, stream>>>(
      logits_bf, smax, sinv, probs);

  // 7) paired PV (narrow core, 256 uniform blocks) + residual + output transpose
  pv_kernel<<<dim3(8, 8, B_DIM), 512, 0, stream>>>(probs, VTd, m_bf, out);
}

// Round 18
// 186.389 us; speedup vs baseline: 1.1027x; 1.1027x over previous
//
#include <hip/hip_runtime.h>

#define T_DIM 2048
#define D_DIM 1024
#define H_DIM 1024
#define B_DIM 4

typedef __attribute__((ext_vector_type(8))) __bf16 bf16x8;
typedef __attribute__((ext_vector_type(4))) float f32x4;
typedef __attribute__((ext_vector_type(8))) unsigned short us8;

__device__ __forceinline__ unsigned short f2b(float f) {
  union { float f; unsigned int u; } x; x.f = f;
  unsigned int r = x.u + 0x7fffu + ((x.u >> 16) & 1u);
  return (unsigned short)(r >> 16);
}
__device__ __forceinline__ float b2f(unsigned short b) {
  union { unsigned int u; float f; } x; x.u = ((unsigned int)b) << 16;
  return x.f;
}

__device__ __forceinline__ void async16(unsigned short* l, const unsigned short* g) {
  __builtin_amdgcn_global_load_lds((const __attribute__((address_space(1))) void*)g,
                                   (__attribute__((address_space(3))) void*)l,
                                   16, 0, 0);
}

// ---------------- fused input prep: weights cvt + bias concat + xT transpose ----------------
__global__ __launch_bounds__(256) void prep_kernel(const float* __restrict__ ew,
                                                   const float* __restrict__ kw,
                                                   const float* __restrict__ qw,
                                                   const float* __restrict__ vw,
                                                   const float* __restrict__ kb,
                                                   const float* __restrict__ qb,
                                                   const float* __restrict__ vb,
                                                   const float* __restrict__ X,
                                                   unsigned short* __restrict__ oe,
                                                   unsigned short* __restrict__ okqv,
                                                   float* __restrict__ ob,
                                                   unsigned short* __restrict__ xT) {
  __shared__ float tile[32][33];
  int bid = blockIdx.x;
  if (bid < 4096) {                 // weight cvt: float4 index over 4 x 256K
    int i = bid * 256 + threadIdx.x;
    int seg = i >> 18;
    int off = i & 262143;
    const float* in = seg == 0 ? ew : (seg == 1 ? kw : (seg == 2 ? qw : vw));
    unsigned short* out = seg == 0 ? oe : okqv + (size_t)(seg - 1) * 1048576;
    float4 v = ((const float4*)in)[off];
    ushort4 o;
    o.x = f2b(v.x); o.y = f2b(v.y); o.z = f2b(v.z); o.w = f2b(v.w);
    ((ushort4*)out)[off] = o;
    return;
  }
  if (bid == 4096) {                // bias concat: 3072 floats
    #pragma unroll
    for (int k = 0; k < 3; k++) {
      int f4 = threadIdx.x + k * 256;
      int fi = f4 * 4;
      const float* src = fi < 1024 ? kb + fi : (fi < 2048 ? qb + (fi - 1024) : vb + (fi - 2048));
      *(float4*)(&ob[fi]) = *(const float4*)src;
    }
    return;
  }
  // xT transpose
  int v = bid - 4097;
  int c0 = (v & 63) * 32;           // t
  int r0 = ((v >> 6) & 31) * 32;    // h
  int z  = v >> 11;                 // batch
  int tx = threadIdx.x & 31, ty = threadIdx.x >> 5;
  const float* I = X + (size_t)z * H_DIM * T_DIM;
  #pragma unroll
  for (int i = 0; i < 32; i += 8)
    tile[ty + i][tx] = I[(size_t)(r0 + ty + i) * T_DIM + (c0 + tx)];
  __syncthreads();
  unsigned short* O = xT + (size_t)z * T_DIM * H_DIM;
  #pragma unroll
  for (int i = 0; i < 32; i += 8)
    O[(size_t)(c0 + ty + i) * H_DIM + (r0 + tx)] = f2b(tile[tx][ty + i]);
}

#define BAR_ asm volatile("s_barrier" ::: "memory")
#define VM8_ asm volatile("s_waitcnt vmcnt(8)" ::: "memory")
#define VM6_ asm volatile("s_waitcnt vmcnt(6)" ::: "memory")
#define VM4_ asm volatile("s_waitcnt vmcnt(4)" ::: "memory")
#define VM0_ asm volatile("s_waitcnt vmcnt(0)" ::: "memory")

#define FRG(base, row, ks) \
  (*(const bf16x8*)((base) + (row) * 64 + ((((ks) << 2) | hi) ^ (lo & 7)) * 8))

// ---- 128x256 triple-buffer core macros ----
#define STGA3(t, bb, u) async16(smem + (bb) * 24576 + (u) * 4096 + tid * 8, \
                                A + (size_t)((u) * 64 + rl0) * lda + (t) * 64 + ce)
#define STGB3(t, bb, u) async16(smem + (bb) * 24576 + 8192 + (u) * 4096 + tid * 8, \
                                Bm + (size_t)((u) * 64 + rl0) * ldb + (t) * 64 + ce)
#define STGTILE(t, bb) do { STGA3(t, bb, 0); STGA3(t, bb, 1); \
    STGB3(t, bb, 0); STGB3(t, bb, 1); STGB3(t, bb, 2); STGB3(t, bb, 3); } while (0)

#define LOADFRAGS(bA, bB)                                            \
  _Pragma("unroll") for (int m_ = 0; m_ < 4; m_++) {                 \
    af[m_][0] = FRG(bA, wr * 64 + m_ * 16 + lo, 0);                  \
    af[m_][1] = FRG(bA, wr * 64 + m_ * 16 + lo, 1);                  \
  }                                                                  \
  _Pragma("unroll") for (int n_ = 0; n_ < 4; n_++) {                 \
    bg[n_][0] = FRG(bB, wc * 64 + n_ * 16 + lo, 0);                  \
    bg[n_][1] = FRG(bB, wc * 64 + n_ * 16 + lo, 1);                  \
  }

#define MFMA32_                                                          \
  __builtin_amdgcn_s_setprio(1);                                         \
  _Pragma("unroll") for (int ks_ = 0; ks_ < 2; ks_++)                    \
    _Pragma("unroll") for (int m_ = 0; m_ < 4; m_++)                     \
      _Pragma("unroll") for (int n_ = 0; n_ < 4; n_++)                   \
        acc[m_][n_] = __builtin_amdgcn_mfma_f32_16x16x32_bf16(           \
            af[m_][ks_], bg[n_][ks_], acc[m_][n_], 0, 0, 0);             \
  __builtin_amdgcn_s_setprio(0);

// 128x256 triple-buffer GEMM body (OMODE 1: col bias; 3: row bias).
#define GEMM8_BODY(OMODE, Apar, Bpar, biasPar, CbPar, Npar, Kpar, ldaPar, ldbPar, flatPar, gxPar, gyPar) \
  do {                                                                                 \
    int nwg = (gxPar) * (gyPar);                                                       \
    int cpx = nwg >> 3;                                                                \
    int f2 = ((flatPar) & 7) * cpx + ((flatPar) >> 3);                                 \
    int bn = f2 % (gxPar), bm = f2 / (gxPar);                                          \
    const unsigned short* A  = (Apar) + (size_t)bm * 128 * (ldaPar);                   \
    const unsigned short* Bm = (Bpar) + (size_t)bn * 256 * (ldbPar);                   \
    int lda = (ldaPar), ldb = (ldbPar);                                                \
    int nt = (Kpar) / 64;                                                              \
    bf16x8 af[4][2], bg[4][2];                                                         \
    f32x4 acc[4][4] = {};                                                              \
    STGTILE(0, 0);                                                                     \
    STGTILE(1, 1);                                                                     \
    VM6_; BAR_;                                                                        \
    int cur = 0;                                                                       \
    for (int t = 0; t < nt - 2; t++) {                                                 \
      const unsigned short* bA = smem + cur * 24576;                                   \
      const unsigned short* bB = bA + 8192;                                            \
      LOADFRAGS(bA, bB)                                                                \
      int b2 = cur + 2; if (b2 >= 3) b2 -= 3;                                          \
      STGTILE(t + 2, b2);                                                              \
      MFMA32_                                                                          \
      VM6_; BAR_;                                                                      \
      cur = (cur + 1 == 3) ? 0 : cur + 1;                                              \
    }                                                                                  \
    {                                                                                  \
      const unsigned short* bA = smem + cur * 24576;                                   \
      const unsigned short* bB = bA + 8192;                                            \
      LOADFRAGS(bA, bB)                                                                \
      MFMA32_                                                                          \
      VM0_; BAR_;                                                                      \
      cur = (cur + 1 == 3) ? 0 : cur + 1;                                              \
    }                                                                                  \
    {                                                                                  \
      const unsigned short* bA = smem + cur * 24576;                                   \
      const unsigned short* bB = bA + 8192;                                            \
      LOADFRAGS(bA, bB)                                                                \
      MFMA32_                                                                          \
    }                                                                                  \
    __syncthreads();                                                                   \
    int row0 = bm * 128, col0 = bn * 256;                                              \
    unsigned short* ep = smem;                                                         \
    _Pragma("unroll") for (int n = 0; n < 4; n++) {                                    \
      int cl = wc * 64 + n * 16 + lo;                                                  \
      float bvc = ((OMODE) == 1) ? (biasPar)[col0 + cl] : 0.f;                         \
      _Pragma("unroll") for (int m = 0; m < 4; m++) {                                  \
        int rl = wr * 64 + m * 16 + hi * 4;                                            \
        _Pragma("unroll") for (int j = 0; j < 4; j++) {                                \
          float bv = ((OMODE) == 3) ? (biasPar)[row0 + rl + j] : bvc;                  \
          ep[(rl + j) * 264 + cl] = f2b(acc[m][n][j] + bv);                            \
        }                                                                              \
      }                                                                                \
    }                                                                                  \
    __syncthreads();                                                                   \
    _Pragma("unroll") for (int it = 0; it < 8; it++) {                                 \
      int idx = it * 512 + tid, r = idx >> 5, c = idx & 31;                            \
      *(uint4*)((CbPar) + (size_t)(row0 + r) * (Npar) + col0 + c * 8) =                \
          *(const uint4*)(ep + r * 264 + c * 8);                                       \
    }                                                                                  \
  } while (0)

template <int OMODE>
__global__ __launch_bounds__(512, 2)
void gemm8_kernel(const unsigned short* __restrict__ Ag,
                  const unsigned short* __restrict__ Bg,
                  const float* __restrict__ bias,
                  unsigned short* __restrict__ Cb,
                  int N, int K, int lda_, int ldb_) {
  __shared__ __align__(16) unsigned short smem[73728];   // 144 KiB
  int tid = threadIdx.x;
  int lane = tid & 63, wid = tid >> 6;
  int wr = wid >> 2, wc = wid & 3;
  int lo = lane & 15, hi = lane >> 4;
  int rl0 = tid >> 3;
  int ce = 8 * ((tid & 7) ^ (rl0 & 7));
  int flat = blockIdx.x + gridDim.x * blockIdx.y;
  GEMM8_BODY(OMODE, Ag, Bg, bias, Cb, N, K, lda_, ldb_, flat, (int)gridDim.x, (int)gridDim.y);
}

// ---- 256x256 8-phase core macros (R7-validated ledger) ----
#define STGAH(t, h) do { \
    unsigned short* d_ = ldsA + ((t) & 1) * 16384 + (h) * 8192 + tid * 8;            \
    const unsigned short* s_ = A + (size_t)((h) * 128 + rl0) * lda + (t) * 64 + ce;  \
    async16(d_, s_); async16(d_ + 4096, s_ + (size_t)64 * lda); } while (0)
#define STGBH(t, h) do { \
    unsigned short* d_ = ldsB + ((t) & 1) * 16384 + (h) * 8192 + tid * 8;            \
    const unsigned short* s_ = Bm + (size_t)((h) * 128 + rl0) * ldb + (t) * 64 + ce; \
    async16(d_, s_); async16(d_ + 4096, s_ + (size_t)64 * ldb); } while (0)

#define LDA_(bA, mb)                                                   \
  _Pragma("unroll") for (int m_ = 0; m_ < 4; m_++) {                   \
    int row_ = wr * 128 + ((mb) + m_) * 16 + lo;                       \
    af[m_][0] = FRG(bA, row_, 0);                                      \
    af[m_][1] = FRG(bA, row_, 1);                                      \
  }

#define LDB_(bB, nb, bgv)                                              \
  _Pragma("unroll") for (int n_ = 0; n_ < 2; n_++) {                   \
    int row_ = wc * 64 + ((nb) + n_) * 16 + lo;                        \
    bgv[n_][0] = FRG(bB, row_, 0);                                     \
    bgv[n_][1] = FRG(bB, row_, 1);                                     \
  }

#define MM_(mb, nb, bgv)                                                             \
  __builtin_amdgcn_s_setprio(1);                                                     \
  _Pragma("unroll") for (int m_ = 0; m_ < 4; m_++)                                   \
    _Pragma("unroll") for (int n_ = 0; n_ < 2; n_++) {                               \
      acc[(mb) + m_][(nb) + n_] = __builtin_amdgcn_mfma_f32_16x16x32_bf16(           \
          af[m_][0], bgv[n_][0], acc[(mb) + m_][(nb) + n_], 0, 0, 0);                \
      acc[(mb) + m_][(nb) + n_] = __builtin_amdgcn_mfma_f32_16x16x32_bf16(           \
          af[m_][1], bgv[n_][1], acc[(mb) + m_][(nb) + n_], 0, 0, 0);                \
    }                                                                                \
  __builtin_amdgcn_s_setprio(0);

#define GEMML_BODY(BIAS, Apar, Bpar, biasPar, CbPar, Npar, Kpar, ldaPar, ldbPar, bnv, bmv, coffPar) \
  do {                                                                                 \
    const unsigned short* A  = (Apar) + (size_t)(bmv) * 256 * (ldaPar);                \
    const unsigned short* Bm = (Bpar) + (size_t)(bnv) * 256 * (ldbPar);                \
    int lda = (ldaPar), ldb = (ldbPar);                                                \
    unsigned short* ldsA = smem;                                                       \
    unsigned short* ldsB = smem + 32768;                                               \
    int nt = (Kpar) / 64;                                                              \
    bf16x8 af[4][2], bg0[2][2], bg1[2][2];                                             \
    f32x4 acc[8][4] = {};                                                              \
    STGAH(0, 0); STGAH(0, 1); STGBH(0, 0); STGBH(0, 1);                                \
    STGAH(1, 0); STGAH(1, 1); STGBH(1, 0); STGBH(1, 1);                                \
    VM8_; BAR_;                                                                        \
    const unsigned short* bA0 = ldsA;                                                  \
    const unsigned short* bB0 = ldsB;                                                  \
    const unsigned short* bA1 = ldsA + 16384;                                          \
    const unsigned short* bB1 = ldsB + 16384;                                          \
    int nIter = nt >> 1;                                                               \
    for (int i = 0; i < nIter; i++) {                                                  \
      bool last = (i == nIter - 1);                                                    \
      int ta = 2 * i, tb = ta + 1;                                                     \
      LDA_(bA0, 0) LDB_(bB0, 0, bg0)                                                   \
      BAR_; MM_(0, 0, bg0) BAR_;                                                       \
      LDB_(bB0, 2, bg1)                                                                \
      BAR_; MM_(0, 2, bg1) BAR_;                                                       \
      LDA_(bA0, 4)                                                                     \
      if (!last) STGBH(ta + 2, 0);                                                     \
      BAR_; MM_(4, 0, bg0) BAR_;                                                       \
      if (!last) { STGAH(ta + 2, 0); STGBH(ta + 2, 1); }                               \
      BAR_; MM_(4, 2, bg1)                                                             \
      if (last) { VM0_; } else { VM6_; }                                               \
      BAR_;                                                                            \
      LDA_(bA1, 0) LDB_(bB1, 0, bg0)                                                   \
      if (!last) STGAH(ta + 2, 1);                                                     \
      BAR_; MM_(0, 0, bg0) BAR_;                                                       \
      LDB_(bB1, 2, bg1)                                                                \
      BAR_; MM_(0, 2, bg1) BAR_;                                                       \
      LDA_(bA1, 4)                                                                     \
      if (!last) STGBH(tb + 2, 0);                                                     \
      BAR_; MM_(4, 0, bg0) BAR_;                                                       \
      if (!last) { STGAH(tb + 2, 0); STGBH(tb + 2, 1); STGAH(tb + 2, 1); }             \
      BAR_; MM_(4, 2, bg1)                                                             \
      if (!last) VM8_;                                                                 \
      BAR_;                                                                            \
    }                                                                                  \
    __syncthreads();                                                                   \
    int row0 = (bmv) * 256, col0 = (bnv) * 256;                                        \
    unsigned short* ep = smem;                                                         \
    _Pragma("unroll") for (int half = 0; half < 2; half++) {                           \
      __syncthreads();                                                                 \
      if (wr == half) {                                                                \
        _Pragma("unroll") for (int n = 0; n < 4; n++) {                                \
          int cl = wc * 64 + n * 16 + lo;                                              \
          float bv = (BIAS) ? (biasPar)[col0 + cl] : 0.f;                              \
          _Pragma("unroll") for (int m = 0; m < 8; m++) {                              \
            int rl = m * 16 + hi * 4;                                                  \
            _Pragma("unroll") for (int j = 0; j < 4; j++)                              \
              ep[(rl + j) * 264 + cl] = f2b(acc[m][n][j] + bv);                        \
          }                                                                            \
        }                                                                              \
      }                                                                                \
      __syncthreads();                                                                 \
      _Pragma("unroll") for (int it = 0; it < 8; it++) {                               \
        int idx = it * 512 + tid, r = idx >> 5, c = idx & 31;                          \
        *(uint4*)((CbPar) + (coffPar) + (size_t)(row0 + half * 128 + r) * (Npar) +     \
                  col0 + c * 8) = *(const uint4*)(ep + r * 264 + c * 8);               \
      }                                                                                \
    }                                                                                  \
  } while (0)

// KQ = m @ [Wk;Wq]^T + b : standalone, 256 blocks (1 exact round)
__global__ __launch_bounds__(512, 2)
void gemmKQ_kernel(const unsigned short* __restrict__ m_bf,
                   const unsigned short* __restrict__ wbf_kqv,
                   const float* __restrict__ kqv_b,
                   unsigned short* __restrict__ KQ) {
  __shared__ __align__(16) unsigned short smem[73728];
  int tid = threadIdx.x;
  int lane = tid & 63, wid = tid >> 6;
  int wr = wid >> 2, wc = wid & 3;
  int lo = lane & 15, hi = lane >> 4;
  int rl0 = tid >> 3;
  int ce = 8 * ((tid & 7) ^ (rl0 & 7));
  int flat = blockIdx.x;
  int f2x = (flat & 7) * 32 + (flat >> 3);
  int bn = f2x % 8, bm = f2x / 8;
  GEMML_BODY(true, m_bf, wbf_kqv, kqv_b, KQ, 2048, D_DIM, D_DIM, D_DIM, bn, bm,
             (size_t)0);
}

// Merged VTd (blocks 0..255, 128x256 core) + logits (blocks 256..511, 256^2 core).
__global__ __launch_bounds__(512, 2)
void lvt_kernel(const unsigned short* __restrict__ KQ,
                const unsigned short* __restrict__ m_bf,
                const unsigned short* __restrict__ wbf_kqv,
                const float* __restrict__ value_b,
                unsigned short* __restrict__ logits_bf,
                unsigned short* __restrict__ VTd) {
  __shared__ __align__(16) unsigned short smem[73728];
  int tid = threadIdx.x;
  int lane = tid & 63, wid = tid >> 6;
  int wr = wid >> 2, wc = wid & 3;
  int lo = lane & 15, hi = lane >> 4;
  int rl0 = tid >> 3;
  int ce = 8 * ((tid & 7) ^ (rl0 & 7));

  if (blockIdx.x < 256) {
    // VTd[d][bt] = Wv[d]·m[bt] + vb[d] : M=1024 (8 tiles of 128), N=8192 (32 tiles)
    int flat = blockIdx.x;
    GEMM8_BODY(3, wbf_kqv + 2 * 1024 * 1024, m_bf, value_b, VTd, 8192, D_DIM,
               D_DIM, D_DIM, flat, 32, 8);
  } else {
    // logitsT[b][s][t] = K[b,s]·Q[b,t], causal skip (bn<bm)
    int lbid = blockIdx.x - 256;
    int bz = lbid >> 6;
    int flat = lbid & 63;
    int f2x = (flat & 7) * 8 + (flat >> 3);
    int bn = f2x % 8, bm = f2x / 8;
    if (bn < bm) return;
    const unsigned short* Ab = KQ + (size_t)bz * T_DIM * 2048;
    const unsigned short* Bb = KQ + 1024 + (size_t)bz * T_DIM * 2048;
    GEMML_BODY(false, Ab, Bb, (const float*)nullptr, logits_bf, T_DIM, D_DIM,
               2048, 2048, bn, bm, (size_t)bz * T_DIM * T_DIM);
  }
}

// ============ Paired causal PV (R11/R13 version, measured 39us) ============
#define PSTGA(t, bb, u) async16(smem + (bb) * 16384 + (u) * 4096 + tid * 8, \
                                Ap + (size_t)((u) * 64 + rl0) * T_DIM + (t) * 64 + ce)
#define PSTGB(t, bb, u) async16(smem + (bb) * 16384 + 8192 + (u) * 4096 + tid * 8, \
                                Bp + (size_t)((u) * 64 + rl0) * 8192 + (t) * 64 + ce)
#define PSTG(t, bb) do { PSTGA(t, bb, 0); PSTGA(t, bb, 1); \
                         PSTGB(t, bb, 0); PSTGB(t, bb, 1); } while (0)

#define PVFRAGS(bA, bB)                                              \
  _Pragma("unroll") for (int m_ = 0; m_ < 4; m_++) {                 \
    af[m_][0] = FRG(bA, wr * 64 + m_ * 16 + lo, 0);                  \
    af[m_][1] = FRG(bA, wr * 64 + m_ * 16 + lo, 1);                  \
  }                                                                  \
  _Pragma("unroll") for (int n_ = 0; n_ < 2; n_++) {                 \
    bg[n_][0] = FRG(bB, wc * 32 + n_ * 16 + lo, 0);                  \
    bg[n_][1] = FRG(bB, wc * 32 + n_ * 16 + lo, 1);                  \
  }

#define PVMFMA_                                                          \
  __builtin_amdgcn_s_setprio(1);                                         \
  _Pragma("unroll") for (int ks_ = 0; ks_ < 2; ks_++)                    \
    _Pragma("unroll") for (int m_ = 0; m_ < 4; m_++)                     \
      _Pragma("unroll") for (int n_ = 0; n_ < 2; n_++)                   \
        acc[m_][n_] = __builtin_amdgcn_mfma_f32_16x16x32_bf16(           \
            af[m_][ks_], bg[n_][ks_], acc[m_][n_], 0, 0, 0);             \
  __builtin_amdgcn_s_setprio(0);

__global__ __launch_bounds__(512, 2)
void pv_kernel(const unsigned short* __restrict__ probs,
               const unsigned short* __restrict__ VTd,
               const unsigned short* __restrict__ mres,
               float* __restrict__ out) {
  __shared__ __align__(16) unsigned short smem[49152];   // 96 KiB
  int bn = blockIdx.x;        // d-tile (128 wide), 0..7
  int jj = blockIdx.y;        // pair id 0..7
  int bz = blockIdx.z;
  int tid = threadIdx.x;
  int lane = tid & 63, wid = tid >> 6;
  int wr = wid >> 2, wc = wid & 3;      // wr: t-half, wc: d-quarter
  int lo = lane & 15, hi = lane >> 4;
  int rl0 = tid >> 3;
  int ce = 8 * ((tid & 7) ^ (rl0 & 7));

  const unsigned short* Bp = VTd + (size_t)(bn * 128) * 8192 + bz * T_DIM;

  #pragma unroll 1
  for (int seg = 0; seg < 2; seg++) {
    int jt = (seg == 0) ? jj : (15 - jj);
    int nt = ((seg == 0) ? (jj + 1) : (16 - jj)) * 2;
    const unsigned short* Ap = probs + (size_t)bz * T_DIM * T_DIM + (size_t)(jt * 128) * T_DIM;

    bf16x8 af[4][2], bg[2][2];
    f32x4 acc[4][2] = {};

    PSTG(0, 0);
    PSTG(1, 1);
    VM4_; BAR_;

    int cur = 0;
    for (int t = 0; t < nt - 2; t++) {
      const unsigned short* bA = smem + cur * 16384;
      const unsigned short* bB = bA + 8192;
      PVFRAGS(bA, bB)
      int b2 = cur + 2; if (b2 >= 3) b2 -= 3;
      PSTG(t + 2, b2);
      PVMFMA_
      VM4_; BAR_;
      cur = (cur + 1 == 3) ? 0 : cur + 1;
    }
    {
      const unsigned short* bA = smem + cur * 16384;
      const unsigned short* bB = bA + 8192;
      PVFRAGS(bA, bB)
      PVMFMA_
      VM0_; BAR_;
      cur = (cur + 1 == 3) ? 0 : cur + 1;
    }
    {
      const unsigned short* bA = smem + cur * 16384;
      const unsigned short* bB = bA + 8192;
      PVFRAGS(bA, bB)
      PVMFMA_
    }

    __syncthreads();
    float* ep = (float*)smem;   // [128 d][132 t]
    #pragma unroll
    for (int n = 0; n < 2; n++) {
      int dl = wc * 32 + n * 16 + lo;
      #pragma unroll
      for (int m = 0; m < 4; m++) {
        int tl = wr * 64 + m * 16 + hi * 4;
        #pragma unroll
        for (int j = 0; j < 4; j++) {
          float v = acc[m][n][j] +
              b2f(mres[((size_t)bz * T_DIM + jt * 128 + tl + j) * D_DIM + bn * 128 + dl]);
          ep[dl * 132 + tl + j] = v;
        }
      }
    }
    __syncthreads();
    #pragma unroll
    for (int it = 0; it < 8; it++) {
      int idx = it * 512 + tid, r = idx >> 5, c = idx & 31;
      *(float4*)(out + ((size_t)bz * D_DIM + bn * 128 + r) * T_DIM + jt * 128 + c * 4) =
          *(const float4*)(ep + r * 132 + c * 4);
    }
    __syncthreads();
  }
}

// ---------------- softmax stats (bf16 logitsT rows, causal start) ----------------
__device__ __forceinline__ float wred_max(float v) {
  #pragma unroll
  for (int o = 32; o > 0; o >>= 1) v = fmaxf(v, __shfl_down(v, o, 64));
  return v;
}
__device__ __forceinline__ float wred_sum(float v) {
  #pragma unroll
  for (int o = 32; o > 0; o >>= 1) v += __shfl_down(v, o, 64);
  return v;
}

__global__ __launch_bounds__(256) void softmax_stats_kernel(const unsigned short* __restrict__ lg,
                                                            float* __restrict__ smax,
                                                            float* __restrict__ sinv) {
  __shared__ float sb[4];
  int row = blockIdx.x;            // b*T + s
  int s = row & (T_DIM - 1);
  int t0 = s & ~255;               // 256-aligned causal floor
  int n8 = (T_DIM - t0) >> 3;
  float x[8];
  float mx = -3.4e38f;
  if (threadIdx.x < n8) {
    us8 v = ((const us8*)(lg + (size_t)row * T_DIM + t0))[threadIdx.x];
    int tb = t0 + threadIdx.x * 8;
    #pragma unroll
    for (int j = 0; j < 8; j++) {
      x[j] = (tb + j >= s) ? b2f(v[j]) : -3.4e38f;
      mx = fmaxf(mx, x[j]);
    }
  } else {
    #pragma unroll
    for (int j = 0; j < 8; j++) x[j] = -3.4e38f;
  }
  mx = wred_max(mx);
  if ((threadIdx.x & 63) == 0) sb[threadIdx.x >> 6] = mx;
  __syncthreads();
  mx = fmaxf(fmaxf(sb[0], sb[1]), fmaxf(sb[2], sb[3]));
  __syncthreads();
  float sum = 0.f;
  #pragma unroll
  for (int j = 0; j < 8; j++) sum += __expf(x[j] - mx);
  sum = wred_sum(sum);
  if ((threadIdx.x & 63) == 0) sb[threadIdx.x >> 6] = sum;
  __syncthreads();
  if (threadIdx.x == 0) {
    float tot = sb[0] + sb[1] + sb[2] + sb[3];
    smax[row] = mx;
    sinv[row] = 1.0f / (tot * 32.0f);
  }
}

// ---------------- normalize + transpose: probs[t][s] bf16 ----------------
__global__ __launch_bounds__(256) void probs_kernel(const unsigned short* __restrict__ lg,
                                                    const float* __restrict__ smax,
                                                    const float* __restrict__ sinv,
                                                    unsigned short* __restrict__ probs) {
  int bz = blockIdx.z;
  int t0 = blockIdx.x * 32, s0 = blockIdx.y * 32;
  if (s0 >= (((t0 >> 7) + 1) << 7)) return;
  __shared__ unsigned short tile[32][33];
  int tx = threadIdx.x & 31, ty = threadIdx.x >> 5;
  const unsigned short* L = lg + (size_t)bz * T_DIM * T_DIM;
  #pragma unroll
  for (int i = 0; i < 32; i += 8)
    tile[ty + i][tx] = L[(size_t)(s0 + ty + i) * T_DIM + (t0 + tx)];
  __syncthreads();
  unsigned short* P = probs + (size_t)bz * T_DIM * T_DIM;
  #pragma unroll
  for (int i = 0; i < 32; i += 8) {
    int t = t0 + ty + i, s = s0 + tx;
    float x = b2f(tile[tx][ty + i]);
    float p = (t >= s) ? __expf(x - smax[bz * T_DIM + s]) * sinv[bz * T_DIM + s] : 0.f;
    P[(size_t)t * T_DIM + s] = f2b(p);
  }
}

extern "C" void kernel_launch(void* const* d_in, const int* in_sizes, int n_in,
                              void* d_out, int out_size, void* d_ws, size_t ws_size,
                              hipStream_t stream) {
  const float* minibatch = (const float*)d_in[0];
  const float* emb_w   = (const float*)d_in[1];
  const float* emb_b   = (const float*)d_in[2];
  const float* key_w   = (const float*)d_in[3];
  const float* key_b   = (const float*)d_in[4];
  const float* query_w = (const float*)d_in[5];
  const float* query_b = (const float*)d_in[6];
  const float* value_w = (const float*)d_in[7];
  const float* value_b = (const float*)d_in[8];
  float* out = (float*)d_out;

  char* ws = (char*)d_ws;
  const size_t MB = 1ull << 20;
  unsigned short* wbf_emb = (unsigned short*)(ws + 0 * MB);    // 2 MB
  unsigned short* wbf_kqv = (unsigned short*)(ws + 2 * MB);    // 6 MB [key|query|value]
  float*          kqv_b   = (float*)(ws + 8 * MB);
  unsigned short* m_bf    = (unsigned short*)(ws + 9 * MB);    // 16 MB, live to end
  unsigned short* KQ      = (unsigned short*)(ws + 25 * MB);   // 32 MB [8192][2048]
  unsigned short* VTd     = (unsigned short*)(ws + 57 * MB);   // 16 MB [1024][8192]
  unsigned short* logits_bf = (unsigned short*)(ws + 89 * MB); // 32 MB
  unsigned short* xT      = (unsigned short*)(ws + 153 * MB);  // 16 MB (dead after emb)
  unsigned short* probs   = (unsigned short*)(ws + 153 * MB);  // 32 MB, aliases xT
  float*          smax    = (float*)(ws + 186 * MB);
  float*          sinv    = (float*)(ws + 186 * MB + 32768);

  const int BT = B_DIM * T_DIM;   // 8192

  // 1) fused: weights -> bf16, bias concat, xT transpose
  prep_kernel<<<12289, 256, 0, stream>>>(emb_w, key_w, query_w, value_w,
                                         key_b, query_b, value_b, minibatch,
                                         wbf_emb, wbf_kqv, kqv_b, xT);

  // 2) m = xT @ emb_w^T + emb_b  -- 128x256 tile, 256 blocks, 1 round
  gemm8_kernel<1><<<dim3(D_DIM / 256, BT / 128, 1), 512, 0, stream>>>(
      xT, wbf_emb, emb_b, m_bf, D_DIM, H_DIM, H_DIM, H_DIM);

  // 3) KQ = m @ [Wk;Wq]^T + b  -- 256^2 core, 256 blocks, 1 exact round
  gemmKQ_kernel<<<256, 512, 0, stream>>>(m_bf, wbf_kqv, kqv_b, KQ);

  // 4) merged: VTd (blocks 0..255) + logits (blocks 256..511, causal skip)
  lvt_kernel<<<512, 512, 0, stream>>>(KQ, m_bf, wbf_kqv, value_b, logits_bf, VTd);

  // 5) column-softmax stats (causal-trimmed reads)
  softmax_stats_kernel<<<BT, 256, 0, stream>>>(logits_bf, smax, sinv);

  // 6) probs[b][t][s] bf16, transposed
  probs_kernel<<<dim3(T_DIM / 32, T_DIM / 32, B_DIM), 256, 0, stream>>>(
      logits_bf, smax, sinv, probs);

  // 7) paired PV (narrow core, 256 uniform blocks) + residual + output transpose
  pv_kernel<<<dim3(8, 8, B_DIM), 512, 0, stream>>>(probs, VTd, m_bf, out);
}